// Round 3
// baseline (2324.344 us; speedup 1.0000x reference)
//
#include <hip/hip_runtime.h>
#include <math.h>

// SoftSkeletonize via the erosion-chain identity:
//   e_0 = img, e_{i+1} = erode(e_i)   (erode = min(vmin3, hmin3), +inf pad)
//   delta_i = relu(e_i - dilate3x3(e_{i+1}))   (dilate = vmax3(hmax3), -inf pad)
//   skel: s = delta_0, then s += relu(delta_i - s*delta_i), i = 1..40
//
// 5 fused phases (K = 9,8,8,8,8). 64x64 tile + halo staged in LDS ping-pong.
// Round-3 change: ALL LDS traffic is ds_read/write_b128 (no scalar b32
// neighbor reads -- those were 8-way bank-conflicted because stride and strip
// spacing are both 0 mod 4, pinning a whole wave into one 8-bank residue
// class). Halo scalars come from the edge elements of b128@(o-4)/b128@(o+8).
// Thread patches are 2 rows x 8 cols for vertical register reuse.

#define HH 1024
#define WW 1024
#define T 64
#define MT 12                    // top/left margin
#define MB 10                    // bottom/right margin
#define REG_H (MT + T + MB)      // 86 rows
#define STRIDE 88                // floats per LDS row
#define NTHREADS 512

#define LD4(p)    (*(const float4*)(p))
#define ST4(p, v) (*(float4*)(p) = (v))

__device__ __forceinline__ float relu_(float x) { return x > 0.f ? x : 0.f; }
__device__ __forceinline__ float min3_(float a, float b, float c) { return fminf(a, fminf(b, c)); }
__device__ __forceinline__ float max3_(float a, float b, float c) { return fmaxf(a, fmaxf(b, c)); }
__device__ __forceinline__ float4 min4_(float4 a, float4 b) {
    return make_float4(fminf(a.x,b.x), fminf(a.y,b.y), fminf(a.z,b.z), fminf(a.w,b.w));
}
__device__ __forceinline__ float4 max4_(float4 a, float4 b) {
    return make_float4(fmaxf(a.x,b.x), fmaxf(a.y,b.y), fmaxf(a.z,b.z), fmaxf(a.w,b.w));
}
// horizontal 3-tap min over 9 scalars L,a0..a3,b0..b3,R -> two output quads
__device__ __forceinline__ void hmin9(float L, float4 a, float4 b, float R,
                                      float4& h0, float4& h1) {
    h0.x = min3_(L,   a.x, a.y); h0.y = min3_(a.x, a.y, a.z);
    h0.z = min3_(a.y, a.z, a.w); h0.w = min3_(a.z, a.w, b.x);
    h1.x = min3_(a.w, b.x, b.y); h1.y = min3_(b.x, b.y, b.z);
    h1.z = min3_(b.y, b.z, b.w); h1.w = min3_(b.z, b.w, R);
}
__device__ __forceinline__ void hmax9(float L, float4 a, float4 b, float R,
                                      float4& h0, float4& h1) {
    h0.x = max3_(L,   a.x, a.y); h0.y = max3_(a.x, a.y, a.z);
    h0.z = max3_(a.y, a.z, a.w); h0.w = max3_(a.z, a.w, b.x);
    h1.x = max3_(a.w, b.x, b.y); h1.y = max3_(b.x, b.y, b.z);
    h1.z = max3_(b.y, b.z, b.w); h1.w = max3_(b.z, b.w, R);
}
__device__ __forceinline__ void skup(float4& s, float4 e, float4 d, bool init) {
    float4 dl;
    dl.x = relu_(e.x - d.x); dl.y = relu_(e.y - d.y);
    dl.z = relu_(e.z - d.z); dl.w = relu_(e.w - d.w);
    if (init) { s = dl; }
    else {
        s.x += relu_(dl.x - s.x * dl.x); s.y += relu_(dl.y - s.y * dl.y);
        s.z += relu_(dl.z - s.z * dl.z); s.w += relu_(dl.w - s.w * dl.w);
    }
}

__global__ __launch_bounds__(NTHREADS, 4) void phase_kernel(
    const float* __restrict__ src, float* __restrict__ dst,
    float* __restrict__ skel, int K, int first, int last)
{
    __shared__ __align__(16) float Abuf[REG_H * STRIDE];
    __shared__ __align__(16) float Bbuf[REG_H * STRIDE];

    const int h0 = blockIdx.y * T;
    const int w0 = blockIdx.x * T;
    const size_t plane = (size_t)HH * WW;
    const float* sp = src + blockIdx.z * plane;
    float* skp = skel + blockIdx.z * plane;
    float* dp = dst ? dst + blockIdx.z * plane : nullptr;

    const int tid = threadIdx.x;
    const bool interior = (h0 >= MT) && (w0 >= MT) &&
                          (h0 + T + MB <= HH) && (w0 + T + MB <= WW);

    float* cur = Abuf;
    float* nxt = Bbuf;

    if (interior) {
        // ---- stage region rows [h0-MT, h0+T+MB) x cols [w0-MT, w0-MT+STRIDE)
        {
            const float* base = sp + (size_t)(h0 - MT) * WW + (w0 - MT);
            for (int idx = tid; idx < REG_H * (STRIDE / 4); idx += NTHREADS) {
                int r = idx / (STRIDE / 4);
                int q = idx - r * (STRIDE / 4);
                ST4(&Abuf[r * STRIDE + 4 * q], LD4(base + (size_t)r * WW + 4 * q));
            }
        }
        // skel accumulators: thread tid<256 owns rows 2p,2p+1 x cols 8s..8s+7
        const int ds_ = tid & 7, dpi = tid >> 3;           // dilate strip/rowpair
        float4 sk00, sk01, sk10, sk11;
        if (!first && tid < 256) {
            const float* g = skp + (size_t)(h0 + 2 * dpi) * WW + (w0 + 8 * ds_);
            sk00 = LD4(g); sk01 = LD4(g + 4);
            sk10 = LD4(g + WW); sk11 = LD4(g + WW + 4);
        }
        __syncthreads();

        for (int j = 0; j < K; ++j) {
            // ---- erode cur -> nxt: rows 1..84, 11 strips of 8 => 462 patches
            if (tid < 462) {
                const int s = tid % 11, p = tid / 11;
                const int o = (1 + 2 * p) * STRIDE + 8 * s;
                float4 U0 = LD4(cur + o - STRIDE), U1 = LD4(cur + o - STRIDE + 4);
                float4 Am = LD4(cur + o - 4),          A0 = LD4(cur + o);
                float4 A1 = LD4(cur + o + 4),          A2 = LD4(cur + o + 8);
                float4 Bm = LD4(cur + o + STRIDE - 4), B0 = LD4(cur + o + STRIDE);
                float4 B1 = LD4(cur + o + STRIDE + 4), B2 = LD4(cur + o + STRIDE + 8);
                float4 D0 = LD4(cur + o + 2 * STRIDE), D1 = LD4(cur + o + 2 * STRIDE + 4);
                float4 P0 = min4_(A0, B0), P1 = min4_(A1, B1);
                float4 h0q, h1q;
                hmin9(Am.w, A0, A1, A2.x, h0q, h1q);
                float4 e00 = min4_(min4_(U0, P0), h0q);
                float4 e01 = min4_(min4_(U1, P1), h1q);
                hmin9(Bm.w, B0, B1, B2.x, h0q, h1q);
                float4 e10 = min4_(min4_(P0, D0), h0q);
                float4 e11 = min4_(min4_(P1, D1), h1q);
                ST4(nxt + o, e00);          ST4(nxt + o + 4, e01);
                ST4(nxt + o + STRIDE, e10); ST4(nxt + o + STRIDE + 4, e11);
            }
            __syncthreads();
            // ---- dilate(nxt) + delta(cur) + skel, central 64x64: 256 patches
            if (tid < 256) {
                const int o = (MT + 2 * dpi) * STRIDE + (MT + 8 * ds_);
                float4 hm00, hm01, hm10, hm11, hm20, hm21, hm30, hm31;
                {
                    int q = o - STRIDE;
                    float4 M = LD4(nxt + q - 4), X0 = LD4(nxt + q),
                           X1 = LD4(nxt + q + 4), X2 = LD4(nxt + q + 8);
                    hmax9(M.w, X0, X1, X2.x, hm00, hm01);
                }
                {
                    int q = o;
                    float4 M = LD4(nxt + q - 4), X0 = LD4(nxt + q),
                           X1 = LD4(nxt + q + 4), X2 = LD4(nxt + q + 8);
                    hmax9(M.w, X0, X1, X2.x, hm10, hm11);
                }
                {
                    int q = o + STRIDE;
                    float4 M = LD4(nxt + q - 4), X0 = LD4(nxt + q),
                           X1 = LD4(nxt + q + 4), X2 = LD4(nxt + q + 8);
                    hmax9(M.w, X0, X1, X2.x, hm20, hm21);
                }
                {
                    int q = o + 2 * STRIDE;
                    float4 M = LD4(nxt + q - 4), X0 = LD4(nxt + q),
                           X1 = LD4(nxt + q + 4), X2 = LD4(nxt + q + 8);
                    hmax9(M.w, X0, X1, X2.x, hm30, hm31);
                }
                float4 d00 = max4_(hm00, max4_(hm10, hm20));
                float4 d01 = max4_(hm01, max4_(hm11, hm21));
                float4 d10 = max4_(hm10, max4_(hm20, hm30));
                float4 d11 = max4_(hm11, max4_(hm21, hm31));
                float4 E00 = LD4(cur + o),          E01 = LD4(cur + o + 4);
                float4 E10 = LD4(cur + o + STRIDE), E11 = LD4(cur + o + STRIDE + 4);
                const bool init = (first && j == 0);
                skup(sk00, E00, d00, init); skup(sk01, E01, d01, init);
                skup(sk10, E10, d10, init); skup(sk11, E11, d11, init);
            }
            __syncthreads();
            float* t = cur; cur = nxt; nxt = t;
        }
        // ---- write skel
        if (tid < 256) {
            float* g = skp + (size_t)(h0 + 2 * dpi) * WW + (w0 + 8 * ds_);
            ST4(g, sk00); ST4(g + 4, sk01);
            ST4(g + WW, sk10); ST4(g + WW + 4, sk11);
        }
        // ---- write e_K central (next phase input)
        if (!last) {
            for (int k = 0; k < 2; ++k) {
                int q = tid + NTHREADS * k;      // 0..1023 quads
                int rr = q >> 4, qc = (q & 15) << 2;
                float4 v = LD4(cur + (MT + rr) * STRIDE + MT + qc);
                ST4(dp + (size_t)(h0 + rr) * WW + (w0 + qc), v);
            }
        }
    } else {
        // ================= border slow path (60/256 tiles) =================
        for (int idx = tid; idx < REG_H * STRIDE; idx += NTHREADS) {
            int r = idx / STRIDE, c = idx - r * STRIDE;
            int gh = h0 - MT + r, gw = w0 - MT + c;
            float v = INFINITY;
            if (gh >= 0 && gh < HH && gw >= 0 && gw < WW) v = sp[(size_t)gh * WW + gw];
            Abuf[idx] = v;
        }
        float sreg[8];
        if (!first) {
#pragma unroll
            for (int k = 0; k < 8; ++k) {
                int idx = tid + NTHREADS * k;
                int rr = idx >> 6, cc = idx & 63;
                sreg[k] = skp[(size_t)(h0 + rr) * WW + (w0 + cc)];
            }
        }
        __syncthreads();

        for (int j = 0; j < K; ++j) {
            for (int idx = tid; idx < 84 * 86; idx += NTHREADS) {
                int r = 1 + idx / 86;
                int c = 1 + (idx - (r - 1) * 86);
                int gh = h0 - MT + r, gw = w0 - MT + c;
                float v = INFINITY;
                if (gh >= 0 && gh < HH && gw >= 0 && gw < WW) {
                    int o = r * STRIDE + c;
                    v = fminf(fminf(cur[o - STRIDE], cur[o + STRIDE]),
                              min3_(cur[o - 1], cur[o], cur[o + 1]));
                }
                nxt[r * STRIDE + c] = v;
            }
            __syncthreads();
#pragma unroll
            for (int k = 0; k < 8; ++k) {
                int idx = tid + NTHREADS * k;
                int rr = idx >> 6, cc = idx & 63;
                int r = MT + rr, c = MT + cc;
                int gh = h0 + rr, gw = w0 + cc;
                float m = -INFINITY;
#pragma unroll
                for (int dr = -1; dr <= 1; ++dr) {
                    int hr = gh + dr;
                    if (hr < 0 || hr >= HH) continue;
#pragma unroll
                    for (int dc = -1; dc <= 1; ++dc) {
                        int wc = gw + dc;
                        if (wc < 0 || wc >= WW) continue;
                        m = fmaxf(m, nxt[(r + dr) * STRIDE + (c + dc)]);
                    }
                }
                float dl = relu_(cur[r * STRIDE + c] - m);
                if (first && j == 0) sreg[k] = dl;
                else sreg[k] += relu_(dl - sreg[k] * dl);
            }
            __syncthreads();
            float* t = cur; cur = nxt; nxt = t;
        }
#pragma unroll
        for (int k = 0; k < 8; ++k) {
            int idx = tid + NTHREADS * k;
            int rr = idx >> 6, cc = idx & 63;
            skp[(size_t)(h0 + rr) * WW + (w0 + cc)] = sreg[k];
            if (!last) dp[(size_t)(h0 + rr) * WW + (w0 + cc)] = cur[(MT + rr) * STRIDE + (MT + cc)];
        }
    }
}

extern "C" void kernel_launch(void* const* d_in, const int* in_sizes, int n_in,
                              void* d_out, int out_size, void* d_ws, size_t ws_size,
                              hipStream_t stream) {
    const float* img = (const float*)d_in[0];
    float* skel = (float*)d_out;
    const int B = in_sizes[0] / (HH * WW);  // 16
    const size_t plane = (size_t)HH * WW;

    float* e0 = (float*)d_ws;
    float* e1 = e0 + (size_t)B * plane;

    dim3 grid(WW / T, HH / T, B);
    dim3 block(NTHREADS);

    const int Ks[5] = {9, 8, 8, 8, 8};   // 41 chain steps total
    const float* src = img;
    float* bufs[2] = {e0, e1};
    for (int p = 0; p < 5; ++p) {
        int first = (p == 0), last = (p == 4);
        float* dst = last ? nullptr : bufs[p & 1];
        phase_kernel<<<grid, block, 0, stream>>>(src, dst, skel, Ks[p], first, last);
        src = dst;
    }
}

// Round 5
// 989.545 us; speedup vs baseline: 2.3489x; 2.3489x over previous
//
#include <hip/hip_runtime.h>
#include <math.h>

// SoftSkeletonize via the erosion-chain identity:
//   e_0 = img, e_{i+1} = erode(e_i)      (erode = 5-pt cross min, +inf pad)
//   delta_i = relu(e_i - dilate3x3(e_{i+1}))            (dilate pad = -inf)
//   skel: s = delta_0; s += relu(delta_i - s*delta_i), i = 1..40
//
// 5 fused phases (S = 9,8,8,8,8 chain steps). Per 64x64 tile, stage e with
// halo (11 rows / 12 cols) in LDS; S+1 merged passes per phase:
//   pass t: erode e_{t-1}(src buf) -> e_t(dst buf)  [t <= S]
//           delta_{t-2} = relu(e_{t-2} - dilate(e_{t-1}))  [t >= 2]
//   e_{t-2} is read from the dst buffer at the thread's OWN patch before its
//   own overwrite (read-set == write-set per thread -> no extra barrier).
// All LDS traffic is b128 with lane spacing 16B: 8 consecutive lanes cover 8
// consecutive bank quads; +/-4-float shifted reads are a constant rotation
// mod 8 -> conflict-free (round-3's 8-float spacing aliased quads mod 8).
// Border tiles use the same path with +/-INF masks (erode writes forced to
// +inf outside the image; dilate reads forced to -inf outside).
// NOTE: no {buf0,buf1} pointer array — addrspace(3) aggregate init doesn't
// compile on gfx950; buffers are selected by parity ternary instead.

#define HH 1024
#define WW 1024
#define T 64
#define MTR 11                 // top row margin  (central rows start at buf row 11, odd -> row-pairs align)
#define MTC 12                 // left col margin (central cols start at quad 3)
#define RH 86                  // buffer rows
#define STq 22                 // quads per buffer row
#define STRD 88                // floats per buffer row
#define NT 512
#define NIDX 924               // 42 row-pairs x 22 quad-cols

#define LD4(p)    (*(const float4*)(p))
#define ST4(p, v) (*(float4*)(p) = (v))

__device__ __forceinline__ float relu_(float x) { return x > 0.f ? x : 0.f; }
__device__ __forceinline__ float4 min4_(float4 a, float4 b) {
    return make_float4(fminf(a.x,b.x), fminf(a.y,b.y), fminf(a.z,b.z), fminf(a.w,b.w));
}
__device__ __forceinline__ float4 max4_(float4 a, float4 b) {
    return make_float4(fmaxf(a.x,b.x), fmaxf(a.y,b.y), fmaxf(a.z,b.z), fmaxf(a.w,b.w));
}
// 3-tap horizontal min/max of quad a with scalar edges L (col-1), R (col+4)
__device__ __forceinline__ float4 hmin4(float L, float4 a, float R) {
    float4 h;
    h.x = fminf(L,   fminf(a.x, a.y)); h.y = fminf(a.x, fminf(a.y, a.z));
    h.z = fminf(a.y, fminf(a.z, a.w)); h.w = fminf(a.z, fminf(a.w, R));
    return h;
}
__device__ __forceinline__ float4 hmax4(float L, float4 a, float R) {
    float4 h;
    h.x = fmaxf(L,   fmaxf(a.x, a.y)); h.y = fmaxf(a.x, fmaxf(a.y, a.z));
    h.z = fmaxf(a.y, fmaxf(a.z, a.w)); h.w = fmaxf(a.z, fmaxf(a.w, R));
    return h;
}
__device__ __forceinline__ float4 dmask4(float4 v, float rm, float4 cm) {
    // keep if in-image (rm/cm = +INF), else -INF (rm/cm = -INF)
    float4 o;
    o.x = fminf(fminf(v.x, cm.x), rm); o.y = fminf(fminf(v.y, cm.y), rm);
    o.z = fminf(fminf(v.z, cm.z), rm); o.w = fminf(fminf(v.w, cm.w), rm);
    return o;
}
__device__ __forceinline__ void skup(float4& s, float4 e, float4 d, bool init) {
    float4 dl;
    dl.x = relu_(e.x - d.x); dl.y = relu_(e.y - d.y);
    dl.z = relu_(e.z - d.z); dl.w = relu_(e.w - d.w);
    if (init) { s = dl; }
    else {
        s.x += relu_(dl.x - s.x * dl.x); s.y += relu_(dl.y - s.y * dl.y);
        s.z += relu_(dl.z - s.z * dl.z); s.w += relu_(dl.w - s.w * dl.w);
    }
}

__global__ __launch_bounds__(NT, 4) void phase_kernel(
    const float* __restrict__ src, float* __restrict__ dst,
    float* __restrict__ skel, int S, int first, int last)
{
    __shared__ __align__(16) float buf0[RH * STRD + 4];
    __shared__ __align__(16) float buf1[RH * STRD + 4];

    const int h0 = blockIdx.y * T;
    const int w0 = blockIdx.x * T;
    const size_t plane = (size_t)HH * WW;
    const float* sp = src + blockIdx.z * plane;
    float* skp = skel + blockIdx.z * plane;
    float* dp = dst ? dst + blockIdx.z * plane : nullptr;

    const int tid = threadIdx.x;
    const bool border = (h0 == 0) || (w0 == 0) || (h0 + T == HH) || (w0 + T == WW);

    // ---- stage e_{i0} (+inf outside image) into buf0
    if (!border) {
        const float* base = sp + (size_t)(h0 - MTR) * WW + (w0 - MTC);
        for (int i = tid; i < RH * STq; i += NT) {
            int r = i / STq, q = i - r * STq;
            ST4(&buf0[r * STRD + 4 * q], LD4(base + (size_t)r * WW + 4 * q));
        }
    } else {
        for (int i = tid; i < RH * STRD; i += NT) {
            int r = i / STRD, c = i - r * STRD;
            int gh = h0 - MTR + r, gw = w0 - MTC + c;
            float v = INFINITY;
            if ((unsigned)gh < HH && (unsigned)gw < WW) v = sp[(size_t)gh * WW + gw];
            buf0[r * STRD + c] = v;
        }
    }

    // ---- per-round geometry (round q handles idx = tid + NT*q)
    int pq[2], cq[2], oq[2];
    bool act[2], cen[2];
    float4 s0[2], s1[2];
#pragma unroll
    for (int q = 0; q < 2; ++q) {
        int idx = tid + NT * q;
        act[q] = (idx < NIDX);
        int p = idx / STq, c = idx - STq * p;
        pq[q] = p; cq[q] = c;
        oq[q] = (1 + 2 * p) * STRD + 4 * c;
        cen[q] = act[q] && (p >= 5) && (p <= 36) && (c >= 3) && (c <= 18);
    }
    if (!first) {
#pragma unroll
        for (int q = 0; q < 2; ++q) if (cen[q]) {
            const float* g = skp + (size_t)(h0 + 2 * pq[q] - 10) * WW + (w0 + 4 * cq[q] - 12);
            s0[q] = LD4(g); s1[q] = LD4(g + WW);
        }
    }
    __syncthreads();

    for (int t = 1; t <= S + 1; ++t) {
        float* sb = ((t - 1) & 1) ? buf1 : buf0;
        float* db = (t & 1) ? buf1 : buf0;
        const bool do_er = (t <= S);
        const bool do_dl = (t >= 2);
        const bool init = (first != 0) && (t == 2);
#pragma unroll
        for (int q = 0; q < 2; ++q) {
            if (!act[q]) continue;
            const bool cw = cen[q] && do_dl;
            if (!(do_er || cw)) continue;
            const int o = oq[q];
            // shared loads (erode rows r-1..r+2, mid rows with +/-4)
            float4 U   = LD4(sb + o - STRD);
            float4 Am0 = LD4(sb + o - 4);
            float4 A0  = LD4(sb + o);
            float4 Ap0 = LD4(sb + o + 4);
            float4 Am1 = LD4(sb + o + STRD - 4);
            float4 A1  = LD4(sb + o + STRD);
            float4 Ap1 = LD4(sb + o + STRD + 4);
            float4 D   = LD4(sb + o + 2 * STRD);
            float4 ec0, ec1, Um, Up, Dm, Dp;
            if (cw) {   // extra edges for dilate rows r-1, r+2; e_{t-2} own quads (read BEFORE write)
                Um = LD4(sb + o - STRD - 4);
                Up = LD4(sb + o - STRD + 4);
                Dm = LD4(sb + o + 2 * STRD - 4);
                Dp = LD4(sb + o + 2 * STRD + 4);
                ec0 = LD4(db + o);
                ec1 = LD4(db + o + STRD);
            }
            if (do_er) {
                float4 h0q = hmin4(Am0.w, A0, Ap0.x);
                float4 h1q = hmin4(Am1.w, A1, Ap1.x);
                float4 e0 = min4_(min4_(U, A1), h0q);   // min(row r-1, row r+1, hmin row r)
                float4 e1 = min4_(min4_(A0, D), h1q);
                if (border) {   // force +inf outside image
                    int ghb = h0 - MTR + 1 + 2 * pq[q];
                    int gwb = w0 - MTC + 4 * cq[q];
                    float4 cwm;
                    cwm.x = (unsigned)(gwb + 0) < WW ? -INFINITY : INFINITY;
                    cwm.y = (unsigned)(gwb + 1) < WW ? -INFINITY : INFINITY;
                    cwm.z = (unsigned)(gwb + 2) < WW ? -INFINITY : INFINITY;
                    cwm.w = (unsigned)(gwb + 3) < WW ? -INFINITY : INFINITY;
                    float r0 = (unsigned)ghb       < HH ? -INFINITY : INFINITY;
                    float r1 = (unsigned)(ghb + 1) < HH ? -INFINITY : INFINITY;
                    e0 = max4_(e0, max4_(make_float4(r0, r0, r0, r0), cwm));
                    e1 = max4_(e1, max4_(make_float4(r1, r1, r1, r1), cwm));
                }
                ST4(db + o, e0);
                ST4(db + o + STRD, e1);
            }
            if (cw) {
                float4 tU = U, tA = A0, tB = A1, tD = D;
                float eUm = Um.w, eUp = Up.x, eAm = Am0.w, eAp = Ap0.x;
                float eBm = Am1.w, eBp = Ap1.x, eDm = Dm.w, eDp = Dp.x;
                if (border) {   // force -inf outside image before hmax
                    int ghb = h0 - MTR + 1 + 2 * pq[q];
                    int gwb = w0 - MTC + 4 * cq[q];
                    float rm0 = (unsigned)(ghb - 1) < HH ? INFINITY : -INFINITY;
                    float rm1 = (unsigned)(ghb)     < HH ? INFINITY : -INFINITY;
                    float rm2 = (unsigned)(ghb + 1) < HH ? INFINITY : -INFINITY;
                    float rm3 = (unsigned)(ghb + 2) < HH ? INFINITY : -INFINITY;
                    float cmL = (unsigned)(gwb - 1) < WW ? INFINITY : -INFINITY;
                    float cmR = (unsigned)(gwb + 4) < WW ? INFINITY : -INFINITY;
                    float4 cmC;
                    cmC.x = (unsigned)(gwb + 0) < WW ? INFINITY : -INFINITY;
                    cmC.y = (unsigned)(gwb + 1) < WW ? INFINITY : -INFINITY;
                    cmC.z = (unsigned)(gwb + 2) < WW ? INFINITY : -INFINITY;
                    cmC.w = (unsigned)(gwb + 3) < WW ? INFINITY : -INFINITY;
                    tU = dmask4(tU, rm0, cmC); tA = dmask4(tA, rm1, cmC);
                    tB = dmask4(tB, rm2, cmC); tD = dmask4(tD, rm3, cmC);
                    eUm = fminf(fminf(eUm, cmL), rm0); eUp = fminf(fminf(eUp, cmR), rm0);
                    eAm = fminf(fminf(eAm, cmL), rm1); eAp = fminf(fminf(eAp, cmR), rm1);
                    eBm = fminf(fminf(eBm, cmL), rm2); eBp = fminf(fminf(eBp, cmR), rm2);
                    eDm = fminf(fminf(eDm, cmL), rm3); eDp = fminf(fminf(eDp, cmR), rm3);
                }
                float4 hU = hmax4(eUm, tU, eUp);
                float4 hA = hmax4(eAm, tA, eAp);
                float4 hB = hmax4(eBm, tB, eBp);
                float4 hD = hmax4(eDm, tD, eDp);
                float4 d0 = max4_(hU, max4_(hA, hB));
                float4 d1 = max4_(hA, max4_(hB, hD));
                skup(s0[q], ec0, d0, init);
                skup(s1[q], ec1, d1, init);
            }
        }
        __syncthreads();
    }

    // ---- writeback: skel always; e_S central if not last phase
    const float* eb = (S & 1) ? buf1 : buf0;
#pragma unroll
    for (int q = 0; q < 2; ++q) if (cen[q]) {
        size_t grow = (size_t)(h0 + 2 * pq[q] - 10) * WW + (w0 + 4 * cq[q] - 12);
        ST4(skp + grow, s0[q]);
        ST4(skp + grow + WW, s1[q]);
        if (!last) {
            ST4(dp + grow, LD4(eb + oq[q]));
            ST4(dp + grow + WW, LD4(eb + oq[q] + STRD));
        }
    }
}

extern "C" void kernel_launch(void* const* d_in, const int* in_sizes, int n_in,
                              void* d_out, int out_size, void* d_ws, size_t ws_size,
                              hipStream_t stream) {
    const float* img = (const float*)d_in[0];
    float* skel = (float*)d_out;
    const int B = in_sizes[0] / (HH * WW);  // 16
    const size_t plane = (size_t)HH * WW;

    float* e0 = (float*)d_ws;
    float* e1 = e0 + (size_t)B * plane;

    dim3 grid(WW / T, HH / T, B);
    dim3 block(NT);

    const int Ks[5] = {9, 8, 8, 8, 8};   // 41 deltas total (init + 40 iters)
    const float* src = img;
    float* ebufs[2] = {e0, e1};
    for (int p = 0; p < 5; ++p) {
        int first = (p == 0), last = (p == 4);
        float* dstp = last ? nullptr : ebufs[p & 1];
        phase_kernel<<<grid, block, 0, stream>>>(src, dstp, skel, Ks[p], first, last);
        src = dstp;
    }
}